// Round 4
// baseline (238.820 us; speedup 1.0000x reference)
//
#include <hip/hip_runtime.h>
#include <hip/hip_bf16.h>
#include <cstdint>

typedef __attribute__((ext_vector_type(8))) short bf16x8;
typedef __attribute__((ext_vector_type(4))) float f32x4;
using bf16 = __hip_bfloat16;

static __device__ __forceinline__ float tofloat(float x) { return x; }
static __device__ __forceinline__ float tofloat(bf16 x) { return __bfloat162float(x); }
static __device__ __forceinline__ void storeval(float* p, float v) { *p = v; }
static __device__ __forceinline__ void storeval(bf16* p, float v) { *p = __float2bfloat16(v); }

#define MFMA_BF16 __builtin_amdgcn_mfma_f32_16x16x32_bf16

template <int N>
static __device__ __forceinline__ void vm_wait() {
    if constexpr (N == 0) asm volatile("s_waitcnt vmcnt(0)" ::: "memory");
    else if constexpr (N == 4) asm volatile("s_waitcnt vmcnt(4)" ::: "memory");
    else if constexpr (N == 6) asm volatile("s_waitcnt vmcnt(6)" ::: "memory");
}
static __device__ __forceinline__ void lgkm0() {
    asm volatile("s_waitcnt lgkmcnt(0)" ::: "memory");
    __builtin_amdgcn_sched_barrier(0);
}
static __device__ __forceinline__ void phase_bar() {
    __builtin_amdgcn_sched_barrier(0);
    __builtin_amdgcn_s_barrier();
    __builtin_amdgcn_sched_barrier(0);
}
static __device__ __forceinline__ void gl_lds(const bf16* src, char* dst) {
    __builtin_amdgcn_global_load_lds((const __attribute__((address_space(1))) unsigned int*)src,
                                     (__attribute__((address_space(3))) unsigned int*)dst, 16, 0, 0);
}

// ---------------- convert f32 -> bf16 ----------------
__global__ __launch_bounds__(256) void convert_f32_bf16(const float* __restrict__ in,
                                                        bf16* __restrict__ out, long n) {
    long i = ((long)blockIdx.x * blockDim.x + threadIdx.x) * 8;
    if (i >= n) return;
    float4 a = *(const float4*)(in + i);
    float4 b = *(const float4*)(in + i + 4);
    bf16 t[8];
    t[0] = __float2bfloat16(a.x); t[1] = __float2bfloat16(a.y);
    t[2] = __float2bfloat16(a.z); t[3] = __float2bfloat16(a.w);
    t[4] = __float2bfloat16(b.x); t[5] = __float2bfloat16(b.y);
    t[6] = __float2bfloat16(b.z); t[7] = __float2bfloat16(b.w);
    *(uint4*)(out + i) = *(const uint4*)t;
}

// ---------------- transpose (+convert) to bf16, 32x32 tiles ----------------
template <typename SrcT>
__global__ __launch_bounds__(256) void transpose_to_bf16(const SrcT* __restrict__ src, long srcStride,
                                                         long srcBatch, bf16* __restrict__ dst,
                                                         long dstStride, long dstBatch) {
    __shared__ float tile[32][33];
    const SrcT* s = src + (long)blockIdx.z * srcBatch;
    bf16* d = dst + (long)blockIdx.z * dstBatch;
    long r0 = (long)blockIdx.y * 32, c0 = (long)blockIdx.x * 32;
    for (int i = threadIdx.y; i < 32; i += 8)
        tile[i][threadIdx.x] = tofloat(s[(r0 + i) * srcStride + c0 + threadIdx.x]);
    __syncthreads();
    for (int i = threadIdx.y; i < 32; i += 8)
        d[(c0 + i) * dstStride + r0 + threadIdx.x] = __float2bfloat16(tile[threadIdx.x][i]);
}

// ============ m201-style 8-phase 256x256 NT GEMM ============
// C[M,N] = alpha*A[M,K]*B[N,K]^T (+bias). 8 waves (2M x 4N), per-wave 128x64.
// BK=64. Panels: A0/A1 = M-halves 128x64, B0/B1 = N-halves 128x64; 16KB each.
// LDS 128KB: off(type,par) = type*32768 + par*16384, type {A0,A1,B0,B1}.
// Swizzle: 16B granule g of row r stored at g ^ ((r>>1)&7); staging fetches
// pre-swizzled global source so LDS dest stays linear (global_load_lds).
template <typename OutT, bool BIAS>
__global__ __launch_bounds__(512, 2) void gemm8p(
    const bf16* __restrict__ Ag, long lda, long batchA,
    const bf16* __restrict__ Bg, long ldb, long batchB,
    OutT* __restrict__ Cg, long ldc, long batchC,
    const float* __restrict__ bias, int K, float alpha) {
    extern __shared__ __align__(16) char smem[];

    const int tid = threadIdx.x;
    const int wave = tid >> 6, lane = tid & 63, l16 = lane & 15, lhi = lane >> 4;
    const int wm = wave >> 2, wn = wave & 3;

    const long mtile = (long)blockIdx.y * 256;
    const long ntile = (long)blockIdx.x * 256;
    const bf16* A = Ag + (long)blockIdx.z * batchA;
    const bf16* B = Bg + (long)blockIdx.z * batchB;
    OutT* C = Cg + (long)blockIdx.z * batchC;

    // staging: thread tid -> panel row rp0 = tid>>3 (call1: +64), phys granule tid&7;
    // fetches logical granule g = (tid&7) ^ s(rp), s(rp) = (rp>>1)&7 = (tid>>4)&7.
    const int rp0 = tid >> 3;
    const int g8 = ((tid & 7) ^ ((tid >> 4) & 7)) * 8;
    const bf16* pA = A + (mtile + rp0) * lda + g8;
    const bf16* pB = B + (ntile + rp0) * ldb + g8;
    char* ldst = smem + wave * 1024;

#define STAGE(type, par, t)                                                     \
    do {                                                                        \
        const bf16* s_; long ld_;                                               \
        if ((type) < 2) { s_ = pA + ((type) ? 128 * lda : 0) + (long)(t) * 64; ld_ = lda; } \
        else            { s_ = pB + ((type) == 3 ? 128 * ldb : 0) + (long)(t) * 64; ld_ = ldb; } \
        char* d_ = ldst + (type) * 32768 + (par) * 16384;                       \
        gl_lds(s_, d_);                                                         \
        gl_lds(s_ + 64 * ld_, d_ + 8192);                                       \
    } while (0)

    // fragment reads: row-in-panel = (16-mult) + l16 -> s(row) = (l16>>1)&7
    const int swz = (l16 >> 1) & 7;
    const int cb0 = (lhi ^ swz) * 16;        // k-step 0 granule
    const int cb1 = ((4 + lhi) ^ swz) * 16;  // k-step 1 granule
    const char* aBase = smem + wm * 32768 + l16 * 128;
    const char* bBase = smem + (2 + (wn >> 1)) * 32768 + ((wn & 1) * 64 + l16) * 128;

    bf16x8 aq[8], bq[8];
    f32x4 acc[8][4];
#pragma unroll
    for (int m = 0; m < 8; ++m)
#pragma unroll
        for (int n = 0; n < 4; ++n) acc[m][n] = f32x4{0.f, 0.f, 0.f, 0.f};

#define LDA_(par, h)                                                            \
    do {                                                                        \
        const char* p_ = aBase + (par) * 16384 + (h) * 8192;                    \
        aq[0] = *(const bf16x8*)(p_ + 0 * 2048 + cb0);                          \
        aq[1] = *(const bf16x8*)(p_ + 0 * 2048 + cb1);                          \
        aq[2] = *(const bf16x8*)(p_ + 1 * 2048 + cb0);                          \
        aq[3] = *(const bf16x8*)(p_ + 1 * 2048 + cb1);                          \
        aq[4] = *(const bf16x8*)(p_ + 2 * 2048 + cb0);                          \
        aq[5] = *(const bf16x8*)(p_ + 2 * 2048 + cb1);                          \
        aq[6] = *(const bf16x8*)(p_ + 3 * 2048 + cb0);                          \
        aq[7] = *(const bf16x8*)(p_ + 3 * 2048 + cb1);                          \
    } while (0)

#define LDB_(par, nlo)                                                          \
    do {                                                                        \
        const char* p_ = bBase + (par) * 16384 + (nlo) * 2048;                  \
        bq[(nlo)*2 + 0] = *(const bf16x8*)(p_ + 0 * 2048 + cb0);                \
        bq[(nlo)*2 + 1] = *(const bf16x8*)(p_ + 0 * 2048 + cb1);                \
        bq[(nlo)*2 + 2] = *(const bf16x8*)(p_ + 1 * 2048 + cb0);                \
        bq[(nlo)*2 + 3] = *(const bf16x8*)(p_ + 1 * 2048 + cb1);                \
    } while (0)

#define QUAD(h, nlo)                                                            \
    do {                                                                        \
        __builtin_amdgcn_s_setprio(1);                                          \
        _Pragma("unroll")                                                       \
        for (int m_ = 0; m_ < 4; ++m_) {                                        \
            acc[(h)*4 + m_][(nlo)+0] = MFMA_BF16(aq[m_*2+0], bq[(nlo)*2+0], acc[(h)*4 + m_][(nlo)+0], 0, 0, 0); \
            acc[(h)*4 + m_][(nlo)+0] = MFMA_BF16(aq[m_*2+1], bq[(nlo)*2+1], acc[(h)*4 + m_][(nlo)+0], 0, 0, 0); \
            acc[(h)*4 + m_][(nlo)+1] = MFMA_BF16(aq[m_*2+0], bq[(nlo)*2+2], acc[(h)*4 + m_][(nlo)+1], 0, 0, 0); \
            acc[(h)*4 + m_][(nlo)+1] = MFMA_BF16(aq[m_*2+1], bq[(nlo)*2+3], acc[(h)*4 + m_][(nlo)+1], 0, 0, 0); \
        }                                                                       \
        __builtin_amdgcn_s_setprio(0);                                          \
    } while (0)

    const int NT = K / 64;   // >= 4, even
    const int NI = NT / 2;

    // prologue: tile0 all 4 panels + B0,A0 of tile1; vmcnt(4) -> tile0 landed
    STAGE(2, 0, 0); STAGE(0, 0, 0); STAGE(1, 0, 0); STAGE(3, 0, 0);
    STAGE(2, 1, 1); STAGE(0, 1, 1);
    vm_wait<4>();
    phase_bar();

    for (int i = 0; i < NI - 1; ++i) {
        const int t1 = 2 * i + 1;
        // ---- K-tile t0 = 2i (par 0) ----
        LDA_(0, 0); LDB_(0, 0);
        STAGE(1, 1, t1);                       // A1(t1)
        phase_bar(); lgkm0();
        QUAD(0, 0);
        phase_bar();

        LDB_(0, 2);
        STAGE(3, 1, t1);                       // B1(t1)
        phase_bar(); lgkm0();
        QUAD(0, 2);
        phase_bar();

        LDA_(0, 1);
        STAGE(2, 0, t1 + 1);                   // B0(t0+2)
        phase_bar(); lgkm0();
        QUAD(1, 2);
        phase_bar();

        STAGE(0, 0, t1 + 1);                   // A0(t0+2)
        phase_bar();
        QUAD(1, 0);
        vm_wait<4>();                          // tile t1 fully landed
        phase_bar();

        // ---- K-tile t1 (par 1) ----
        LDA_(1, 0); LDB_(1, 0);
        STAGE(1, 0, t1 + 1);                   // A1(t0+2)
        phase_bar(); lgkm0();
        QUAD(0, 0);
        phase_bar();

        LDB_(1, 2);
        STAGE(3, 0, t1 + 1);                   // B1(t0+2)
        phase_bar(); lgkm0();
        QUAD(0, 2);
        phase_bar();

        LDA_(1, 1);
        STAGE(2, 1, t1 + 2);                   // B0(t0+3)
        phase_bar(); lgkm0();
        QUAD(1, 2);
        phase_bar();

        STAGE(0, 1, t1 + 2);                   // A0(t0+3)
        phase_bar();
        QUAD(1, 0);
        vm_wait<4>();                          // tile t0+2 fully landed
        phase_bar();
    }

    // ---- peeled last iter (tiles NT-2, NT-1) ----
    {
        const int t1 = NT - 1;
        LDA_(0, 0); LDB_(0, 0);
        STAGE(1, 1, t1);
        phase_bar(); lgkm0();
        QUAD(0, 0);
        phase_bar();

        LDB_(0, 2);
        STAGE(3, 1, t1);
        phase_bar(); lgkm0();
        QUAD(0, 2);
        phase_bar();

        LDA_(0, 1);
        phase_bar(); lgkm0();
        QUAD(1, 2);
        phase_bar();

        QUAD(1, 0);
        vm_wait<0>();                          // drain: tile NT-1 landed
        phase_bar();

        LDA_(1, 0); LDB_(1, 0);
        phase_bar(); lgkm0();
        QUAD(0, 0);
        phase_bar();

        LDB_(1, 2);
        phase_bar(); lgkm0();
        QUAD(0, 2);
        phase_bar();

        LDA_(1, 1);
        phase_bar(); lgkm0();
        QUAD(1, 2);
        phase_bar();

        QUAD(1, 0);
    }

    // epilogue: C/D frag layout col = lane&15, row = (lane>>4)*4 + reg
#pragma unroll
    for (int n = 0; n < 4; ++n) {
        long col = ntile + wn * 64 + n * 16 + l16;
        float bv = BIAS ? bias[col] : 0.0f;
#pragma unroll
        for (int am = 0; am < 8; ++am) {
            long row = mtile + wm * 128 + (am >> 2) * 64 + (am & 3) * 16 + lhi * 4;
#pragma unroll
            for (int r2 = 0; r2 < 4; ++r2)
                storeval(&C[(row + r2) * ldc + col], acc[am][n][r2] * alpha + bv);
        }
    }
#undef STAGE
#undef LDA_
#undef LDB_
#undef QUAD
}

// ---------------- row softmax: fp32 [rows,2048] -> bf16 IN-PLACE ----------------
__global__ __launch_bounds__(256) void softmax_rows(float* __restrict__ S, int ncols) {
    __shared__ float red[8];
    const long row = blockIdx.x;
    float* srow = S + row * ncols;
    const int tid = threadIdx.x;
    float v[8];
    float4 x0 = ((const float4*)srow)[tid * 2];
    float4 x1 = ((const float4*)srow)[tid * 2 + 1];
    v[0] = x0.x; v[1] = x0.y; v[2] = x0.z; v[3] = x0.w;
    v[4] = x1.x; v[5] = x1.y; v[6] = x1.z; v[7] = x1.w;
    float m = -3.4e38f;
#pragma unroll
    for (int j = 0; j < 8; ++j) m = fmaxf(m, v[j]);
#pragma unroll
    for (int off = 32; off; off >>= 1) m = fmaxf(m, __shfl_xor(m, off));
    if ((tid & 63) == 0) red[tid >> 6] = m;
    __syncthreads();
    m = fmaxf(fmaxf(red[0], red[1]), fmaxf(red[2], red[3]));
    float s = 0.0f;
#pragma unroll
    for (int j = 0; j < 8; ++j) {
        v[j] = __expf(v[j] - m);
        s += v[j];
    }
#pragma unroll
    for (int off = 32; off; off >>= 1) s += __shfl_xor(s, off);
    if ((tid & 63) == 0) red[4 + (tid >> 6)] = s;
    __syncthreads();
    s = red[4] + red[5] + red[6] + red[7];
    float inv = 1.0f / s;
    bf16 o[8];
#pragma unroll
    for (int j = 0; j < 8; ++j) o[j] = __float2bfloat16(v[j] * inv);
    *(uint4*)((bf16*)srow + tid * 8) = *(const uint4*)o;
}

extern "C" void kernel_launch(void* const* d_in, const int* in_sizes, int n_in, void* d_out,
                              int out_size, void* d_ws, size_t ws_size, hipStream_t stream) {
    (void)in_sizes; (void)n_in; (void)out_size;
    const float* x = (const float*)d_in[0];
    const float* w_qkv = (const float*)d_in[1];
    const float* b_qkv = (const float*)d_in[2];
    const float* w_out = (const float*)d_in[3];
    const float* b_out = (const float*)d_in[4];
    float* out = (float*)d_out;

    const int B = 4, S = 2048, D = 1024;

    {
        (void)hipFuncSetAttribute((const void*)&gemm8p<bf16, true>,
                                  hipFuncAttributeMaxDynamicSharedMemorySize, 131072);
        (void)hipFuncSetAttribute((const void*)&gemm8p<float, false>,
                                  hipFuncAttributeMaxDynamicSharedMemorySize, 131072);
        (void)hipFuncSetAttribute((const void*)&gemm8p<bf16, false>,
                                  hipFuncAttributeMaxDynamicSharedMemorySize, 131072);
        (void)hipFuncSetAttribute((const void*)&gemm8p<float, true>,
                                  hipFuncAttributeMaxDynamicSharedMemorySize, 131072);
    }

    char* ws = (char*)d_ws;
    size_t off = 0;
    auto alloc = [&](size_t bytes) {
        char* p = ws + off;
        off += (bytes + 255) & ~(size_t)255;
        return p;
    };
    bf16* xb = (bf16*)alloc((size_t)B * S * D * 2);
    bf16* qkv = (bf16*)alloc((size_t)B * S * 3 * D * 2);
    bf16* wqkvT = (bf16*)alloc((size_t)3 * D * D * 2);
    bf16* woutT = (bf16*)alloc((size_t)D * D * 2);
    bf16* vt = (bf16*)alloc((size_t)B * D * S * 2);
    bf16* ao = (bf16*)alloc((size_t)B * S * D * 2);
    size_t sc_bytes_full = (size_t)B * S * S * 4;
    int NB = (ws_size >= off + sc_bytes_full) ? B : 1;
    float* sc = (float*)alloc((size_t)NB * S * S * 4);

    // 1. x -> bf16
    long nx = (long)B * S * D;
    convert_f32_bf16<<<(int)(nx / 8 / 256), 256, 0, stream>>>(x, xb, nx);

    // 2. weight transposes (+convert)
    dim3 tb(32, 8);
    transpose_to_bf16<float><<<dim3(3 * D / 32, D / 32, 1), tb, 0, stream>>>(
        w_qkv, 3 * D, 0, wqkvT, D, 0);
    transpose_to_bf16<float><<<dim3(D / 32, D / 32, 1), tb, 0, stream>>>(
        w_out, D, 0, woutT, D, 0);

    // 3. QKV GEMM: [8192,3072] = xb @ wqkvT^T + b_qkv
    gemm8p<bf16, true><<<dim3(3 * D / 256, B * S / 256, 1), 512, 131072, stream>>>(
        xb, D, 0, wqkvT, D, 0, qkv, 3 * D, 0, b_qkv, D, 1.0f);

    // 4. V transpose per batch: vt[b][d][t] = qkv[b*S+t][2D+d]
    transpose_to_bf16<bf16><<<dim3(D / 32, S / 32, B), tb, 0, stream>>>(
        qkv + 2 * D, 3 * D, (long)S * 3 * D, vt, S, (long)D * S);

    // 5. attention
    for (int b0 = 0; b0 < B; b0 += NB) {
        const bf16* Qb = qkv + (size_t)b0 * S * 3 * D;
        const bf16* Kb = Qb + D;
        // scores = Q K^T / 32 (fp32)
        gemm8p<float, false><<<dim3(S / 256, S / 256, NB), 512, 131072, stream>>>(
            Qb, 3 * D, (long)S * 3 * D, Kb, 3 * D, (long)S * 3 * D,
            sc, S, (long)S * S, nullptr, D, 0.03125f);
        // softmax in place (bf16 packed into each row's fp32 slot)
        softmax_rows<<<NB * S, 256, 0, stream>>>(sc, S);
        // ao = attn @ vt^T
        gemm8p<bf16, false><<<dim3(D / 256, S / 256, NB), 512, 131072, stream>>>(
            (const bf16*)sc, 2 * S, (long)S * 2 * S,
            vt + (size_t)b0 * D * S, S, (long)D * S,
            ao + (size_t)b0 * S * D, D, (long)S * D, nullptr, S, 1.0f);
    }

    // 6. out proj: out[8192,1024] = ao @ woutT^T + b_out (fp32)
    gemm8p<float, true><<<dim3(D / 256, B * S / 256, 1), 512, 131072, stream>>>(
        ao, D, 0, woutT, D, 0, out, D, 0, b_out, D, 1.0f);
}

// Round 5
// 222.117 us; speedup vs baseline: 1.0752x; 1.0752x over previous
//
#include <hip/hip_runtime.h>
#include <hip/hip_bf16.h>
#include <cstdint>

typedef __attribute__((ext_vector_type(8))) short bf16x8;
typedef __attribute__((ext_vector_type(4))) float f32x4;
using bf16 = __hip_bfloat16;

static __device__ __forceinline__ float tofloat(float x) { return x; }
static __device__ __forceinline__ float tofloat(bf16 x) { return __bfloat162float(x); }
static __device__ __forceinline__ void storeval(float* p, float v) { *p = v; }
static __device__ __forceinline__ void storeval(bf16* p, float v) { *p = __float2bfloat16(v); }

#define MFMA_BF16 __builtin_amdgcn_mfma_f32_16x16x32_bf16

template <int N>
static __device__ __forceinline__ void vm_wait() {
    if constexpr (N == 0) asm volatile("s_waitcnt vmcnt(0)" ::: "memory");
    else if constexpr (N == 6) asm volatile("s_waitcnt vmcnt(6)" ::: "memory");
    else if constexpr (N == 8) asm volatile("s_waitcnt vmcnt(8)" ::: "memory");
}
static __device__ __forceinline__ void lgkm0() {
    asm volatile("s_waitcnt lgkmcnt(0)" ::: "memory");
    __builtin_amdgcn_sched_barrier(0);
}
static __device__ __forceinline__ void phase_bar() {
    __builtin_amdgcn_sched_barrier(0);
    __builtin_amdgcn_s_barrier();
    __builtin_amdgcn_sched_barrier(0);
}
static __device__ __forceinline__ void gl_lds(const bf16* src, char* dst) {
    __builtin_amdgcn_global_load_lds((const __attribute__((address_space(1))) unsigned int*)src,
                                     (__attribute__((address_space(3))) unsigned int*)dst, 16, 0, 0);
}

// ---------------- convert f32 -> bf16 ----------------
__global__ __launch_bounds__(256) void convert_f32_bf16(const float* __restrict__ in,
                                                        bf16* __restrict__ out, long n) {
    long i = ((long)blockIdx.x * blockDim.x + threadIdx.x) * 8;
    if (i >= n) return;
    float4 a = *(const float4*)(in + i);
    float4 b = *(const float4*)(in + i + 4);
    bf16 t[8];
    t[0] = __float2bfloat16(a.x); t[1] = __float2bfloat16(a.y);
    t[2] = __float2bfloat16(a.z); t[3] = __float2bfloat16(a.w);
    t[4] = __float2bfloat16(b.x); t[5] = __float2bfloat16(b.y);
    t[6] = __float2bfloat16(b.z); t[7] = __float2bfloat16(b.w);
    *(uint4*)(out + i) = *(const uint4*)t;
}

// ---------------- transpose (+convert) to bf16, 32x32 tiles ----------------
template <typename SrcT>
__global__ __launch_bounds__(256) void transpose_to_bf16(const SrcT* __restrict__ src, long srcStride,
                                                         long srcBatch, bf16* __restrict__ dst,
                                                         long dstStride, long dstBatch) {
    __shared__ float tile[32][33];
    const SrcT* s = src + (long)blockIdx.z * srcBatch;
    bf16* d = dst + (long)blockIdx.z * dstBatch;
    long r0 = (long)blockIdx.y * 32, c0 = (long)blockIdx.x * 32;
    for (int i = threadIdx.y; i < 32; i += 8)
        tile[i][threadIdx.x] = tofloat(s[(r0 + i) * srcStride + c0 + threadIdx.x]);
    __syncthreads();
    for (int i = threadIdx.y; i < 32; i += 8)
        d[(c0 + i) * dstStride + r0 + threadIdx.x] = __float2bfloat16(tile[threadIdx.x][i]);
}

// ============ deep-pipelined 8-phase NT GEMM: C = alpha*A*B^T (+bias) ============
// BN=256 fixed, BM in {256,128}. 8 waves (2M x 4N), per-wave (BM/2)x64.
// BK=64. Panels: A0/A1 = M-halves (BM/2)x64, B0/B1 = N-halves 128x64.
// LDS: offA(panel,par)=panel*2PA+par*PA; offB(panel,par)=4PA+panel*2PB+par*PB.
// Double-buffered (par = t&1); tile t+2 staged during tile t (6-7 phases ahead);
// ONE counted vmcnt per K-tile (WV = 4+2*LA). Swizzle: 16B granule g of row r at
// phys g^((r>>1)&7); staging pre-swizzles the GLOBAL source (LDS dest stays linear).
template <typename OutT, bool BIAS, int BM>
__global__ __launch_bounds__(512, 2) void gemm8p(
    const bf16* __restrict__ Ag, long lda, long batchA,
    const bf16* __restrict__ Bg, long ldb, long batchB,
    OutT* __restrict__ Cg, long ldc, long batchC,
    const float* __restrict__ bias, int K, float alpha) {
    constexpr int MR = BM / 32;      // m-frags per wave: 8 | 4
    constexpr int LA = BM / 128;     // gl_lds calls per A panel: 2 | 1
    constexpr int PA = BM * 64;      // A panel bytes: 16384 | 8192
    constexpr int PB = 16384;        // B panel bytes
    constexpr int WV = 4 + 2 * LA;   // steady-state counted vmcnt: 8 | 6
    extern __shared__ __align__(16) char smem[];

    const int tid = threadIdx.x;
    const int wave = tid >> 6, lane = tid & 63, l16 = lane & 15, lhi = lane >> 4;
    const int wm = wave >> 2, wn = wave & 3;

    const long mtile = (long)blockIdx.y * BM;
    const long ntile = (long)blockIdx.x * 256;
    const bf16* A = Ag + (long)blockIdx.z * batchA;
    const bf16* B = Bg + (long)blockIdx.z * batchB;
    OutT* C = Cg + (long)blockIdx.z * batchC;

    // staging map: thread -> panel row rp0=tid>>3, phys granule tid&7,
    // logical source granule (tid&7)^((tid>>4)&7)  [s(r)=(r>>1)&7]
    const int rp0 = tid >> 3;
    const int g8 = ((tid & 7) ^ ((tid >> 4) & 7)) * 8;
    const bf16* pA = A + (mtile + rp0) * lda + g8;
    const bf16* pB = B + (ntile + rp0) * ldb + g8;
    const int wb = wave * 1024;

    auto stageB = [&](int par, int t) {  // 4 loads
        const bf16* s0 = pB + (long)t * 64;
        char* d0 = smem + 4 * PA + par * PB + wb;
        gl_lds(s0, d0);
        gl_lds(s0 + 64 * ldb, d0 + 8192);
        const bf16* s1 = s0 + 128 * ldb;
        char* d1 = smem + 4 * PA + 2 * PB + par * PB + wb;
        gl_lds(s1, d1);
        gl_lds(s1 + 64 * ldb, d1 + 8192);
    };
    auto stageA = [&](int par, int t) {  // 2*LA loads
        const bf16* s0 = pA + (long)t * 64;
        char* d0 = smem + par * PA + wb;
        gl_lds(s0, d0);
        if constexpr (LA == 2) gl_lds(s0 + 64 * lda, d0 + 8192);
        const bf16* s1 = s0 + (long)(BM / 2) * lda;
        char* d1 = smem + 2 * PA + par * PA + wb;
        gl_lds(s1, d1);
        if constexpr (LA == 2) gl_lds(s1 + 64 * lda, d1 + 8192);
    };

    // fragment reads: row-in-panel = 16*j + l16 -> s(row) = (l16>>1)&7
    const int swz = (l16 >> 1) & 7;
    const int cb0 = (lhi ^ swz) * 16;        // k-step 0 granule
    const int cb1 = ((4 + lhi) ^ swz) * 16;  // k-step 1 granule
    const char* aBase = smem + wm * 2 * PA + l16 * 128;
    const char* bBase = smem + 4 * PA + (wn >> 1) * 2 * PB + ((wn & 1) * 64 + l16) * 128;

    bf16x8 aq[MR], bq[8];
    f32x4 acc[MR][4];
#pragma unroll
    for (int m = 0; m < MR; ++m)
#pragma unroll
        for (int n = 0; n < 4; ++n) acc[m][n] = f32x4{0.f, 0.f, 0.f, 0.f};

#define LDA_(par, h)                                                           \
    do {                                                                       \
        const char* p_ = aBase + (par) * PA + (h) * (PA / 2);                  \
        _Pragma("unroll")                                                      \
        for (int m_ = 0; m_ < MR / 2; ++m_) {                                  \
            aq[2 * m_]     = *(const bf16x8*)(p_ + m_ * 2048 + cb0);           \
            aq[2 * m_ + 1] = *(const bf16x8*)(p_ + m_ * 2048 + cb1);           \
        }                                                                      \
    } while (0)

#define LDB_(par, nlo)                                                         \
    do {                                                                       \
        const char* p_ = bBase + (par) * PB + (nlo) * 2048;                    \
        bq[(nlo) * 2 + 0] = *(const bf16x8*)(p_ + cb0);                        \
        bq[(nlo) * 2 + 1] = *(const bf16x8*)(p_ + cb1);                        \
        bq[(nlo) * 2 + 2] = *(const bf16x8*)(p_ + 2048 + cb0);                 \
        bq[(nlo) * 2 + 3] = *(const bf16x8*)(p_ + 2048 + cb1);                 \
    } while (0)

#define QUAD_(h, nlo)                                                          \
    do {                                                                       \
        __builtin_amdgcn_s_setprio(1);                                         \
        _Pragma("unroll")                                                      \
        for (int m_ = 0; m_ < MR / 2; ++m_) {                                  \
            acc[(h) * (MR / 2) + m_][(nlo) + 0] =                              \
                MFMA_BF16(aq[2 * m_], bq[(nlo) * 2 + 0], acc[(h) * (MR / 2) + m_][(nlo) + 0], 0, 0, 0); \
            acc[(h) * (MR / 2) + m_][(nlo) + 0] =                              \
                MFMA_BF16(aq[2 * m_ + 1], bq[(nlo) * 2 + 1], acc[(h) * (MR / 2) + m_][(nlo) + 0], 0, 0, 0); \
            acc[(h) * (MR / 2) + m_][(nlo) + 1] =                              \
                MFMA_BF16(aq[2 * m_], bq[(nlo) * 2 + 2], acc[(h) * (MR / 2) + m_][(nlo) + 1], 0, 0, 0); \
            acc[(h) * (MR / 2) + m_][(nlo) + 1] =                              \
                MFMA_BF16(aq[2 * m_ + 1], bq[(nlo) * 2 + 3], acc[(h) * (MR / 2) + m_][(nlo) + 1], 0, 0, 0); \
        }                                                                      \
        __builtin_amdgcn_s_setprio(0);                                         \
    } while (0)

    // MODE 0: stage tile tstage + counted wait; 1: no stage, drain; 2: plain
#define KTILE(par, tstage, MODE)                                               \
    do {                                                                       \
        LDA_(par, 0); LDB_(par, 0);   /* P1 */                                 \
        phase_bar(); lgkm0();                                                  \
        QUAD_(0, 0);                                                           \
        phase_bar();                                                           \
        LDB_(par, 2);                 /* P2 */                                 \
        phase_bar(); lgkm0();                                                  \
        QUAD_(0, 2);                                                           \
        phase_bar();                                                           \
        LDA_(par, 1);                 /* P3 */                                 \
        if (MODE == 0) stageB(par, tstage);                                    \
        phase_bar(); lgkm0();                                                  \
        QUAD_(1, 2);                                                           \
        phase_bar();                                                           \
        if (MODE == 0) stageA(par, tstage); /* P4 */                           \
        QUAD_(1, 0);                                                           \
        if (MODE == 0) vm_wait<WV>();                                          \
        if (MODE == 1) vm_wait<0>();                                           \
        phase_bar();                                                           \
    } while (0)

    const int NT = K / 64;  // even, >= 4

    // prologue: stage tiles 0,1; wait drains tile 0's loads exactly
    stageB(0, 0); stageA(0, 0);
    stageB(1, 1); stageA(1, 1);
    vm_wait<WV>();
    phase_bar();

    for (int t = 0; t < NT - 2; ++t) KTILE(t & 1, t + 2, 0);
    KTILE(0, 0, 1);  // t = NT-2 (NT even -> par 0); drain remaining loads
    KTILE(1, 0, 2);  // t = NT-1

    // epilogue: C/D frag layout col = lane&15, row = (lane>>4)*4 + reg
#pragma unroll
    for (int n = 0; n < 4; ++n) {
        long col = ntile + wn * 64 + n * 16 + l16;
        float bv = BIAS ? bias[col] : 0.0f;
#pragma unroll
        for (int am = 0; am < MR; ++am) {
            const int h_ = am / (MR / 2), mm = am % (MR / 2);
            long row = mtile + wm * (BM / 2) + h_ * (BM / 4) + mm * 16 + lhi * 4;
#pragma unroll
            for (int r2 = 0; r2 < 4; ++r2)
                storeval(&C[(row + r2) * ldc + col], acc[am][n][r2] * alpha + bv);
        }
    }
#undef KTILE
#undef QUAD_
#undef LDB_
#undef LDA_
}

// ---------------- row softmax: fp32 [rows,2048] -> bf16 IN-PLACE ----------------
__global__ __launch_bounds__(256) void softmax_rows(float* __restrict__ S, int ncols) {
    __shared__ float red[8];
    const long row = blockIdx.x;
    float* srow = S + row * ncols;
    const int tid = threadIdx.x;
    float v[8];
    float4 x0 = ((const float4*)srow)[tid * 2];
    float4 x1 = ((const float4*)srow)[tid * 2 + 1];
    v[0] = x0.x; v[1] = x0.y; v[2] = x0.z; v[3] = x0.w;
    v[4] = x1.x; v[5] = x1.y; v[6] = x1.z; v[7] = x1.w;
    float m = -3.4e38f;
#pragma unroll
    for (int j = 0; j < 8; ++j) m = fmaxf(m, v[j]);
#pragma unroll
    for (int off = 32; off; off >>= 1) m = fmaxf(m, __shfl_xor(m, off));
    if ((tid & 63) == 0) red[tid >> 6] = m;
    __syncthreads();
    m = fmaxf(fmaxf(red[0], red[1]), fmaxf(red[2], red[3]));
    float s = 0.0f;
#pragma unroll
    for (int j = 0; j < 8; ++j) {
        v[j] = __expf(v[j] - m);
        s += v[j];
    }
#pragma unroll
    for (int off = 32; off; off >>= 1) s += __shfl_xor(s, off);
    if ((tid & 63) == 0) red[4 + (tid >> 6)] = s;
    __syncthreads();
    s = red[4] + red[5] + red[6] + red[7];
    float inv = 1.0f / s;
    bf16 o[8];
#pragma unroll
    for (int j = 0; j < 8; ++j) o[j] = __float2bfloat16(v[j] * inv);
    *(uint4*)((bf16*)srow + tid * 8) = *(const uint4*)o;
}

extern "C" void kernel_launch(void* const* d_in, const int* in_sizes, int n_in, void* d_out,
                              int out_size, void* d_ws, size_t ws_size, hipStream_t stream) {
    (void)in_sizes; (void)n_in; (void)out_size;
    const float* x = (const float*)d_in[0];
    const float* w_qkv = (const float*)d_in[1];
    const float* b_qkv = (const float*)d_in[2];
    const float* w_out = (const float*)d_in[3];
    const float* b_out = (const float*)d_in[4];
    float* out = (float*)d_out;

    const int B = 4, S = 2048, D = 1024;

    {
        (void)hipFuncSetAttribute((const void*)&gemm8p<bf16, true, 256>,
                                  hipFuncAttributeMaxDynamicSharedMemorySize, 131072);
        (void)hipFuncSetAttribute((const void*)&gemm8p<float, false, 256>,
                                  hipFuncAttributeMaxDynamicSharedMemorySize, 131072);
        (void)hipFuncSetAttribute((const void*)&gemm8p<bf16, false, 128>,
                                  hipFuncAttributeMaxDynamicSharedMemorySize, 98304);
        (void)hipFuncSetAttribute((const void*)&gemm8p<float, true, 128>,
                                  hipFuncAttributeMaxDynamicSharedMemorySize, 98304);
    }

    char* ws = (char*)d_ws;
    size_t off = 0;
    auto alloc = [&](size_t bytes) {
        char* p = ws + off;
        off += (bytes + 255) & ~(size_t)255;
        return p;
    };
    bf16* xb = (bf16*)alloc((size_t)B * S * D * 2);
    bf16* qkv = (bf16*)alloc((size_t)B * S * 3 * D * 2);
    bf16* wqkvT = (bf16*)alloc((size_t)3 * D * D * 2);
    bf16* woutT = (bf16*)alloc((size_t)D * D * 2);
    bf16* vt = (bf16*)alloc((size_t)B * D * S * 2);
    bf16* ao = (bf16*)alloc((size_t)B * S * D * 2);
    size_t sc_bytes_full = (size_t)B * S * S * 4;
    int NB = (ws_size >= off + sc_bytes_full) ? B : 1;
    float* sc = (float*)alloc((size_t)NB * S * S * 4);

    // 1. x -> bf16
    long nx = (long)B * S * D;
    convert_f32_bf16<<<(int)(nx / 8 / 256), 256, 0, stream>>>(x, xb, nx);

    // 2. weight transposes (+convert)
    dim3 tb(32, 8);
    transpose_to_bf16<float><<<dim3(3 * D / 32, D / 32, 1), tb, 0, stream>>>(
        w_qkv, 3 * D, 0, wqkvT, D, 0);
    transpose_to_bf16<float><<<dim3(D / 32, D / 32, 1), tb, 0, stream>>>(
        w_out, D, 0, woutT, D, 0);

    // 3. QKV GEMM: [8192,3072] = xb @ wqkvT^T + b_qkv   (384 blocks, 256x256)
    gemm8p<bf16, true, 256><<<dim3(3 * D / 256, B * S / 256, 1), 512, 131072, stream>>>(
        xb, D, 0, wqkvT, D, 0, qkv, 3 * D, 0, b_qkv, D, 1.0f);

    // 4. V transpose per batch: vt[b][d][t] = qkv[b*S+t][2D+d]
    transpose_to_bf16<bf16><<<dim3(D / 32, S / 32, B), tb, 0, stream>>>(
        qkv + 2 * D, 3 * D, (long)S * 3 * D, vt, S, (long)D * S);

    // 5. attention
    for (int b0 = 0; b0 < B; b0 += NB) {
        const bf16* Qb = qkv + (size_t)b0 * S * 3 * D;
        const bf16* Kb = Qb + D;
        // scores = Q K^T / 32 (fp32)   (256 blocks, 256x256)
        gemm8p<float, false, 256><<<dim3(S / 256, S / 256, NB), 512, 131072, stream>>>(
            Qb, 3 * D, (long)S * 3 * D, Kb, 3 * D, (long)S * 3 * D,
            sc, S, (long)S * S, nullptr, D, 0.03125f);
        // softmax in place (bf16 packed into each row's fp32 slot)
        softmax_rows<<<NB * S, 256, 0, stream>>>(sc, S);
        // ao = attn @ vt^T   (256 blocks, 128x256 mirror tile)
        gemm8p<bf16, false, 128><<<dim3(D / 256, S / 128, NB), 512, 98304, stream>>>(
            (const bf16*)sc, 2 * S, (long)S * 2 * S,
            vt + (size_t)b0 * D * S, S, (long)D * S,
            ao + (size_t)b0 * S * D, D, (long)S * D, nullptr, S, 1.0f);
    }

    // 6. out proj: out[8192,1024] = ao @ woutT^T + b_out   (256 blocks, 128x256)
    gemm8p<float, true, 128><<<dim3(D / 256, B * S / 128, 1), 512, 98304, stream>>>(
        ao, D, 0, woutT, D, 0, out, D, 0, b_out, D, 1.0f);
}

// Round 7
// 211.226 us; speedup vs baseline: 1.1306x; 1.0516x over previous
//
#include <hip/hip_runtime.h>
#include <hip/hip_bf16.h>
#include <cstdint>

typedef __attribute__((ext_vector_type(8))) short bf16x8;
typedef __attribute__((ext_vector_type(4))) float f32x4;
using bf16 = __hip_bfloat16;

static __device__ __forceinline__ float tofloat(float x) { return x; }
static __device__ __forceinline__ float tofloat(bf16 x) { return __bfloat162float(x); }
static __device__ __forceinline__ void storeval(float* p, float v) { *p = v; }
static __device__ __forceinline__ void storeval(bf16* p, float v) { *p = __float2bfloat16(v); }

#define MFMA_BF16 __builtin_amdgcn_mfma_f32_16x16x32_bf16

template <int N>
static __device__ __forceinline__ void vm_wait() {
    if constexpr (N == 0) asm volatile("s_waitcnt vmcnt(0)" ::: "memory");
    else if constexpr (N == 6) asm volatile("s_waitcnt vmcnt(6)" ::: "memory");
    else if constexpr (N == 8) asm volatile("s_waitcnt vmcnt(8)" ::: "memory");
}
static __device__ __forceinline__ void lgkm0() {
    asm volatile("s_waitcnt lgkmcnt(0)" ::: "memory");
    __builtin_amdgcn_sched_barrier(0);  // rule 18: MFMA must not hoist above the wait
}
static __device__ __forceinline__ void bar() { __builtin_amdgcn_s_barrier(); }
// allow ALU/VALU/SALU/MFMA/DS to cross, pin VMEM (gl_lds) — stages can't hoist above
static __device__ __forceinline__ void vmem_fence() { __builtin_amdgcn_sched_barrier(0x38F); }
static __device__ __forceinline__ void gl_lds(const bf16* src, char* dst) {
    __builtin_amdgcn_global_load_lds((const __attribute__((address_space(1))) unsigned int*)src,
                                     (__attribute__((address_space(3))) unsigned int*)dst, 16, 0, 0);
}

// ---------------- convert f32 -> bf16 ----------------
__global__ __launch_bounds__(256) void convert_f32_bf16(const float* __restrict__ in,
                                                        bf16* __restrict__ out, long n) {
    long i = ((long)blockIdx.x * blockDim.x + threadIdx.x) * 8;
    if (i >= n) return;
    float4 a = *(const float4*)(in + i);
    float4 b = *(const float4*)(in + i + 4);
    bf16 t[8];
    t[0] = __float2bfloat16(a.x); t[1] = __float2bfloat16(a.y);
    t[2] = __float2bfloat16(a.z); t[3] = __float2bfloat16(a.w);
    t[4] = __float2bfloat16(b.x); t[5] = __float2bfloat16(b.y);
    t[6] = __float2bfloat16(b.z); t[7] = __float2bfloat16(b.w);
    *(uint4*)(out + i) = *(const uint4*)t;
}

// ---------------- transpose (+convert) to bf16, 32x32 tiles ----------------
template <typename SrcT>
__global__ __launch_bounds__(256) void transpose_to_bf16(const SrcT* __restrict__ src, long srcStride,
                                                         long srcBatch, bf16* __restrict__ dst,
                                                         long dstStride, long dstBatch) {
    __shared__ float tile[32][33];
    const SrcT* s = src + (long)blockIdx.z * srcBatch;
    bf16* d = dst + (long)blockIdx.z * dstBatch;
    long r0 = (long)blockIdx.y * 32, c0 = (long)blockIdx.x * 32;
    for (int i = threadIdx.y; i < 32; i += 8)
        tile[i][threadIdx.x] = tofloat(s[(r0 + i) * srcStride + c0 + threadIdx.x]);
    __syncthreads();
    for (int i = threadIdx.y; i < 32; i += 8)
        d[(c0 + i) * dstStride + r0 + threadIdx.x] = __float2bfloat16(tile[threadIdx.x][i]);
}

// ============ deep-pipelined 8-phase NT GEMM: C = alpha*A*B^T (+bias) ============
// BN=256 fixed, BM in {256,128}. 8 waves (2M x 4N). BK=64.
// Flat 1-D grid (multiple of 8) with XCD-bijective chunked swizzle, x-fast
// within each chunk for A-panel L2 reuse. Minimal pin set (m201-style):
// bare s_barrier; lgkmcnt(0)+sched_barrier(0); VMEM-only fences before stages;
// ONE counted vmcnt per K-tile. Swizzle: granule g of row r at phys g^((r>>1)&7),
// staging pre-swizzles the GLOBAL source so LDS dest stays linear.
// Staging dest = panel + wave*1024 (gl_lds dest is wave-uniform base + lane*16).
template <typename OutT, bool BIAS, int BM>
__global__ __launch_bounds__(512, 2) void gemm8p(
    const bf16* __restrict__ Ag, long lda, long batchA,
    const bf16* __restrict__ Bg, long ldb, long batchB,
    OutT* __restrict__ Cg, long ldc, long batchC,
    const float* __restrict__ bias, int K, float alpha, int nx, int ny) {
    constexpr int MR = BM / 32;      // m-frags per wave: 8 | 4
    constexpr int LA = BM / 128;     // gl_lds calls per A half-stage: 2 | 1
    constexpr int PA = BM * 64;      // A panel bytes: 16384 | 8192
    constexpr int PB = 16384;        // B panel bytes
    constexpr int WV = 4 + 2 * LA;   // counted vmcnt: 8 | 6
    extern __shared__ __align__(16) char smem[];

    const int tid = threadIdx.x;
    const int wave = tid >> 6, lane = tid & 63, l16 = lane & 15, lhi = lane >> 4;
    const int wm = wave >> 2, wn = wave & 3;

    // XCD-bijective swizzle: block o -> logical l; chunk per XCD, x-fast inside
    const int nwg = gridDim.x;
    const int l = (blockIdx.x & 7) * (nwg >> 3) + (blockIdx.x >> 3);
    const int pt = nx * ny;
    const int z = l / pt, rr = l % pt;
    const long mtile = (long)(rr / nx) * BM;
    const long ntile = (long)(rr % nx) * 256;

    const bf16* A = Ag + (long)z * batchA;
    const bf16* B = Bg + (long)z * batchB;
    OutT* C = Cg + (long)z * batchC;

    // staging map: thread -> panel row rp0=tid>>3, phys granule tid&7,
    // logical source granule (tid&7)^((tid>>4)&7)  [s(r)=(r>>1)&7]
    const int rp0 = tid >> 3;
    const int g8 = ((tid & 7) ^ ((tid >> 4) & 7)) * 8;
    const bf16* pA = A + (mtile + rp0) * lda + g8;
    const bf16* pB = B + (ntile + rp0) * ldb + g8;
    const int wb = wave * 1024;   // per-wave dest offset within a panel half

    auto stageB = [&](int par, int t) {  // 4 loads
        const bf16* s0 = pB + (long)t * 64;
        char* d0 = smem + 4 * PA + par * PB + wb;
        gl_lds(s0, d0);
        gl_lds(s0 + 64 * ldb, d0 + 8192);
        const bf16* s1 = s0 + 128 * ldb;
        char* d1 = smem + 4 * PA + 2 * PB + par * PB + wb;
        gl_lds(s1, d1);
        gl_lds(s1 + 64 * ldb, d1 + 8192);
    };
    auto stageA = [&](int par, int t) {  // 2*LA loads
        const bf16* s0 = pA + (long)t * 64;
        char* d0 = smem + par * PA + wb;
        gl_lds(s0, d0);
        if constexpr (LA == 2) gl_lds(s0 + 64 * lda, d0 + 8192);
        const bf16* s1 = s0 + (long)(BM / 2) * lda;
        char* d1 = smem + 2 * PA + par * PA + wb;
        gl_lds(s1, d1);
        if constexpr (LA == 2) gl_lds(s1 + 64 * lda, d1 + 8192);
    };

    // fragment reads: row-in-panel = 16*j + l16 -> s(row) = (l16>>1)&7
    const int swz = (l16 >> 1) & 7;
    const int cb0 = (lhi ^ swz) * 16;        // k-step 0 granule
    const int cb1 = ((4 + lhi) ^ swz) * 16;  // k-step 1 granule
    const char* aBase = smem + wm * 2 * PA + l16 * 128;
    const char* bBase = smem + 4 * PA + (wn >> 1) * 2 * PB + ((wn & 1) * 64 + l16) * 128;

    bf16x8 aq[MR], bq[8];
    f32x4 acc[MR][4];
#pragma unroll
    for (int m = 0; m < MR; ++m)
#pragma unroll
        for (int n = 0; n < 4; ++n) acc[m][n] = f32x4{0.f, 0.f, 0.f, 0.f};

#define LDA_(par, h)                                                           \
    do {                                                                       \
        const char* p_ = aBase + (par) * PA + (h) * (PA / 2);                  \
        _Pragma("unroll")                                                      \
        for (int m_ = 0; m_ < MR / 2; ++m_) {                                  \
            aq[2 * m_]     = *(const bf16x8*)(p_ + m_ * 2048 + cb0);           \
            aq[2 * m_ + 1] = *(const bf16x8*)(p_ + m_ * 2048 + cb1);           \
        }                                                                      \
    } while (0)

#define LDB_(par, nlo)                                                         \
    do {                                                                       \
        const char* p_ = bBase + (par) * PB + (nlo) * 2048;                    \
        bq[(nlo) * 2 + 0] = *(const bf16x8*)(p_ + cb0);                        \
        bq[(nlo) * 2 + 1] = *(const bf16x8*)(p_ + cb1);                        \
        bq[(nlo) * 2 + 2] = *(const bf16x8*)(p_ + 2048 + cb0);                 \
        bq[(nlo) * 2 + 3] = *(const bf16x8*)(p_ + 2048 + cb1);                 \
    } while (0)

#define QUAD_(h, nlo)                                                          \
    do {                                                                       \
        __builtin_amdgcn_s_setprio(1);                                         \
        _Pragma("unroll")                                                      \
        for (int m_ = 0; m_ < MR / 2; ++m_) {                                  \
            acc[(h) * (MR / 2) + m_][(nlo) + 0] =                              \
                MFMA_BF16(aq[2 * m_], bq[(nlo) * 2 + 0], acc[(h) * (MR / 2) + m_][(nlo) + 0], 0, 0, 0); \
            acc[(h) * (MR / 2) + m_][(nlo) + 0] =                              \
                MFMA_BF16(aq[2 * m_ + 1], bq[(nlo) * 2 + 1], acc[(h) * (MR / 2) + m_][(nlo) + 0], 0, 0, 0); \
            acc[(h) * (MR / 2) + m_][(nlo) + 1] =                              \
                MFMA_BF16(aq[2 * m_], bq[(nlo) * 2 + 2], acc[(h) * (MR / 2) + m_][(nlo) + 1], 0, 0, 0); \
            acc[(h) * (MR / 2) + m_][(nlo) + 1] =                              \
                MFMA_BF16(aq[2 * m_ + 1], bq[(nlo) * 2 + 3], acc[(h) * (MR / 2) + m_][(nlo) + 1], 0, 0, 0); \
        }                                                                      \
        __builtin_amdgcn_s_setprio(0);                                         \
    } while (0)

    // MODE 0: stage tile tstage + counted wait; 1: no stage, drain; 2: plain
#define KTILE(par, tstage, MODE)                                               \
    do {                                                                       \
        /* P1 */                                                               \
        LDA_(par, 0); LDB_(par, 0);                                            \
        bar(); lgkm0();                                                        \
        QUAD_(0, 0);                                                           \
        bar();                                                                 \
        /* P2 */                                                               \
        LDB_(par, 2);                                                          \
        bar(); lgkm0();                                                        \
        QUAD_(0, 2);                                                           \
        bar(); vmem_fence();                                                   \
        /* P3: B-par reads all drained by all waves -> safe to restage B */    \
        LDA_(par, 1);                                                          \
        if (MODE == 0) stageB(par, tstage);                                    \
        bar(); lgkm0();                                                        \
        QUAD_(1, 2);                                                           \
        bar(); vmem_fence();                                                   \
        /* P4: A-par reads drained -> safe to restage A */                     \
        if (MODE == 0) stageA(par, tstage);                                    \
        QUAD_(1, 0);                                                           \
        if (MODE == 0) vm_wait<WV>();                                          \
        if (MODE == 1) vm_wait<0>();                                           \
        bar();                                                                 \
    } while (0)

    const int NT = K / 64;  // even, >= 4

    // prologue: stage tiles 0,1; counted wait drains tile 0's loads exactly
    stageB(0, 0); stageA(0, 0);
    stageB(1, 1); stageA(1, 1);
    vm_wait<WV>();
    bar();

    for (int t = 0; t < NT - 2; ++t) KTILE(t & 1, t + 2, 0);
    KTILE(0, 0, 1);  // t = NT-2 (par 0); drain remaining loads
    KTILE(1, 0, 2);  // t = NT-1

    // epilogue: C/D frag layout col = lane&15, row = (lane>>4)*4 + reg
#pragma unroll
    for (int n = 0; n < 4; ++n) {
        long col = ntile + wn * 64 + n * 16 + l16;
        float bv = BIAS ? bias[col] : 0.0f;
#pragma unroll
        for (int am = 0; am < MR; ++am) {
            const int h_ = am / (MR / 2), mm = am % (MR / 2);
            long row = mtile + wm * (BM / 2) + h_ * (BM / 4) + mm * 16 + lhi * 4;
#pragma unroll
            for (int r2 = 0; r2 < 4; ++r2)
                storeval(&C[(row + r2) * ldc + col], acc[am][n][r2] * alpha + bv);
        }
    }
#undef KTILE
#undef QUAD_
#undef LDB_
#undef LDA_
}

// ---------------- row softmax: bf16 [rows,2048] -> bf16 IN-PLACE ----------------
__global__ __launch_bounds__(256) void softmax_rows_bf16(bf16* __restrict__ S, int ncols) {
    __shared__ float red[8];
    const long row = blockIdx.x;
    bf16* srow = S + row * ncols;
    const int tid = threadIdx.x;
    uint4 raw = *(const uint4*)(srow + tid * 8);
    const bf16* rb = (const bf16*)&raw;
    float v[8];
#pragma unroll
    for (int j = 0; j < 8; ++j) v[j] = __bfloat162float(rb[j]);
    float m = -3.4e38f;
#pragma unroll
    for (int j = 0; j < 8; ++j) m = fmaxf(m, v[j]);
#pragma unroll
    for (int off = 32; off; off >>= 1) m = fmaxf(m, __shfl_xor(m, off));
    if ((tid & 63) == 0) red[tid >> 6] = m;
    __syncthreads();
    m = fmaxf(fmaxf(red[0], red[1]), fmaxf(red[2], red[3]));
    float s = 0.0f;
#pragma unroll
    for (int j = 0; j < 8; ++j) {
        v[j] = __expf(v[j] - m);
        s += v[j];
    }
#pragma unroll
    for (int off = 32; off; off >>= 1) s += __shfl_xor(s, off);
    if ((tid & 63) == 0) red[4 + (tid >> 6)] = s;
    __syncthreads();
    s = red[4] + red[5] + red[6] + red[7];
    float inv = 1.0f / s;
    bf16 o[8];
#pragma unroll
    for (int j = 0; j < 8; ++j) o[j] = __float2bfloat16(v[j] * inv);
    *(uint4*)(srow + tid * 8) = *(const uint4*)o;
}

extern "C" void kernel_launch(void* const* d_in, const int* in_sizes, int n_in, void* d_out,
                              int out_size, void* d_ws, size_t ws_size, hipStream_t stream) {
    (void)in_sizes; (void)n_in; (void)out_size; (void)ws_size;
    const float* x = (const float*)d_in[0];
    const float* w_qkv = (const float*)d_in[1];
    const float* b_qkv = (const float*)d_in[2];
    const float* w_out = (const float*)d_in[3];
    const float* b_out = (const float*)d_in[4];
    float* out = (float*)d_out;

    const int B = 4, S = 2048, D = 1024;

    {
        (void)hipFuncSetAttribute((const void*)&gemm8p<bf16, true, 256>,
                                  hipFuncAttributeMaxDynamicSharedMemorySize, 131072);
        (void)hipFuncSetAttribute((const void*)&gemm8p<bf16, false, 256>,
                                  hipFuncAttributeMaxDynamicSharedMemorySize, 131072);
        (void)hipFuncSetAttribute((const void*)&gemm8p<bf16, false, 128>,
                                  hipFuncAttributeMaxDynamicSharedMemorySize, 98304);
        (void)hipFuncSetAttribute((const void*)&gemm8p<float, true, 128>,
                                  hipFuncAttributeMaxDynamicSharedMemorySize, 98304);
    }

    char* ws = (char*)d_ws;
    size_t off = 0;
    auto alloc = [&](size_t bytes) {
        char* p = ws + off;
        off += (bytes + 255) & ~(size_t)255;
        return p;
    };
    bf16* xb = (bf16*)alloc((size_t)B * S * D * 2);        // 16 MiB
    bf16* qkv = (bf16*)alloc((size_t)B * S * 3 * D * 2);   // 48 MiB
    bf16* wqkvT = (bf16*)alloc((size_t)3 * D * D * 2);     // 6 MiB
    bf16* woutT = (bf16*)alloc((size_t)D * D * 2);         // 2 MiB
    bf16* vt = (bf16*)alloc((size_t)B * D * S * 2);        // 16 MiB
    bf16* ao = (bf16*)alloc((size_t)B * S * D * 2);        // 16 MiB
    bf16* sc = (bf16*)alloc((size_t)B * S * S * 2);        // 33.5 MiB (bf16 scores)

    // 1. x -> bf16
    long nx_ = (long)B * S * D;
    convert_f32_bf16<<<(int)(nx_ / 8 / 256), 256, 0, stream>>>(x, xb, nx_);

    // 2. weight transposes (+convert)
    dim3 tb(32, 8);
    transpose_to_bf16<float><<<dim3(3 * D / 32, D / 32, 1), tb, 0, stream>>>(
        w_qkv, 3 * D, 0, wqkvT, D, 0);
    transpose_to_bf16<float><<<dim3(D / 32, D / 32, 1), tb, 0, stream>>>(
        w_out, D, 0, woutT, D, 0);

    // 3. QKV GEMM: [8192,3072] = xb @ wqkvT^T + b_qkv   (384 blocks, 256x256)
    gemm8p<bf16, true, 256><<<384, 512, 131072, stream>>>(
        xb, D, 0, wqkvT, D, 0, qkv, 3 * D, 0, b_qkv, D, 1.0f, 3 * D / 256, B * S / 256);

    // 4. V transpose per batch: vt[b][d][t] = qkv[b*S+t][2D+d]
    transpose_to_bf16<bf16><<<dim3(D / 32, S / 32, B), tb, 0, stream>>>(
        qkv + 2 * D, 3 * D, (long)S * 3 * D, vt, S, (long)D * S);

    // 5a. scores = Q K^T / 32, bf16 out   (256 blocks, 256x256, all batches)
    gemm8p<bf16, false, 256><<<256, 512, 131072, stream>>>(
        qkv, 3 * D, (long)S * 3 * D, qkv + D, 3 * D, (long)S * 3 * D,
        sc, S, (long)S * S, nullptr, D, 0.03125f, S / 256, S / 256);

    // 5b. softmax in place over bf16 rows
    softmax_rows_bf16<<<B * S, 256, 0, stream>>>(sc, S);

    // 5c. ao = attn @ vt^T   (256 blocks, 128x256, all batches)
    gemm8p<bf16, false, 128><<<256, 512, 98304, stream>>>(
        sc, S, (long)S * S, vt, S, (long)D * S,
        ao, D, (long)S * D, nullptr, S, 1.0f, D / 256, S / 128);

    // 6. out proj: out[8192,1024] = ao @ woutT^T + b_out (fp32)   (256 blocks)
    gemm8p<float, true, 128><<<256, 512, 98304, stream>>>(
        ao, D, 0, woutT, D, 0, out, D, 0, b_out, D, 1.0f, D / 256, B * S / 128);
}